// Round 12
// baseline (1614.872 us; speedup 1.0000x reference)
//
#include <hip/hip_runtime.h>
#include <math.h>
#include <stdint.h>

#define NBOX 2048

// p1 layout: [32 ch][23 rows][25 cols (23 valid + 2 pad)], ch stride 576 floats.
#define P1_RS 25
#define P1_CS 576
#define P1_SZ 18432

__device__ __forceinline__ void fma4(float4& a, float s, const float4& w) {
  a.x = fmaf(s, w.x, a.x); a.y = fmaf(s, w.y, a.y);
  a.z = fmaf(s, w.z, a.z); a.w = fmaf(s, w.w, a.w);
}
__device__ __forceinline__ float4 max4(float4 a, float4 b) {
  return make_float4(fmaxf(a.x,b.x), fmaxf(a.y,b.y), fmaxf(a.z,b.z), fmaxf(a.w,b.w));
}
__device__ __forceinline__ float4 max34(float4 a, float4 b, float4 c) {
  return max4(max4(a, b), c);
}
__device__ __forceinline__ float4 prelu4(float4 v, float4 a) {
  float4 r;
  r.x = v.x >= 0.f ? v.x : a.x*v.x;
  r.y = v.y >= 0.f ? v.y : a.y*v.y;
  r.z = v.z >= 0.f ? v.z : a.z*v.z;
  r.w = v.w >= 0.f ? v.w : a.w*v.w;
  return r;
}
__device__ __forceinline__ float4 shfl4(float4 v, int src) {
  float4 r;
  r.x = __shfl(v.x, src, 64); r.y = __shfl(v.y, src, 64);
  r.z = __shfl(v.z, src, 64); r.w = __shfl(v.w, src, 64);
  return r;
}

// ---------------- K1 (R5-proven, 256 threads): crop+conv1+prelu+pool -> p1T -------
// SESSION LAW: K1's per-slot live state (~100+ VGPRs) spills at 512 threads
// (R10: 2.5 GB scratch writes, 2.3x regression). Keep 256 threads.
__global__ __launch_bounds__(256) void k1_crop_conv1(
    const float* __restrict__ bboxes, const float* __restrict__ image,
    const float* __restrict__ w1, const float* __restrict__ b1, const float* __restrict__ a1,
    float* __restrict__ p1ws, int box0)
{
  __shared__ float crop[48*48*3];
  const int tid = threadIdx.x;
  const int n = box0 + blockIdx.x;

  float f0 = bboxes[n*4+0], f1 = bboxes[n*4+1], f2 = bboxes[n*4+2], f3 = bboxes[n*4+3];
  float bx1 = fmaxf(f0, 0.f), by1 = fmaxf(f1, 0.f);
  float bx2 = fminf(f2, 1024.f), by2 = fminf(f3, 1024.f);
  int ix1 = (int)bx1, iy1 = (int)by1, ix2 = (int)bx2, iy2 = (int)by2;
  int cw = ix2 - ix1; if (cw < 1) cw = 1;
  int ch = iy2 - iy1; if (ch < 1) ch = 1;

  for (int idx = tid; idx < 6912; idx += 256) {
    int c = idx % 3; int t = idx / 3; int j = t % 48; int i = t / 48;
    int gx = ix1 + (j * cw) / 48;
    int gy = iy1 + (i * ch) / 48;
    float v = image[(gy*1024 + gx)*3 + c];
    crop[idx] = (v - 127.5f) * 0.0078125f;
  }
  __syncthreads();

  float* p1o = p1ws + (size_t)blockIdx.x * P1_SZ;

  for (int slot = tid; slot < 1104; slot += 256) {  // 23 * 6 * 8
    int cq = slot & 7;
    int t2 = slot >> 3;
    int pjq = t2 % 6;
    int pi  = t2 / 6;
    int pj0 = pjq * 4;
    int c0 = 2*pj0 - 1;
    float4 bias  = *(const float4*)&b1[cq*4];
    float4 alpha = *(const float4*)&a1[cq*4];
    float4 mx[4];
#pragma unroll
    for (int t = 0; t < 4; t++) mx[t] = make_float4(-3.0e38f,-3.0e38f,-3.0e38f,-3.0e38f);

#pragma unroll
    for (int dr = 0; dr < 3; dr++) {
      int r = 2*pi - 1 + dr;
      if (r < 0 || r > 45) continue;
      float4 acc[9];
#pragma unroll
      for (int c = 0; c < 9; c++) acc[c] = bias;
#pragma unroll
      for (int kh = 0; kh < 3; kh++) {
        int row = r + kh;
        float s[33];
#pragma unroll
        for (int d = 0; d < 11; d++) {
          int cc = c0 + d; cc = cc < 0 ? 0 : (cc > 47 ? 47 : cc);
          int base = row*144 + cc*3;
          s[d*3+0] = crop[base+0];
          s[d*3+1] = crop[base+1];
          s[d*3+2] = crop[base+2];
        }
#pragma unroll
        for (int kw = 0; kw < 3; kw++) {
#pragma unroll
          for (int ci = 0; ci < 3; ci++) {
            float4 w = *(const float4*)&w1[((kh*3+kw)*3+ci)*32 + cq*4];
#pragma unroll
            for (int c = 0; c < 9; c++) fma4(acc[c], s[(c+kw)*3+ci], w);
          }
        }
      }
#pragma unroll
      for (int c = 0; c < 9; c++) {
        int cabs = c0 + c;
        if (cabs < 0 || cabs > 45) continue;
        float4 pv = prelu4(acc[c], alpha);
#pragma unroll
        for (int t = 0; t < 4; t++) {
          if (c >= 2*t && c <= 2*t+2) mx[t] = max4(mx[t], pv);
        }
      }
    }
#pragma unroll
    for (int t = 0; t < 4; t++) {
      int pj = pj0 + t;
      if (pj < 23) {
        int base = pi*P1_RS + pj;
        p1o[(cq*4+0)*P1_CS + base] = mx[t].x;
        p1o[(cq*4+1)*P1_CS + base] = mx[t].y;
        p1o[(cq*4+2)*P1_CS + base] = mx[t].z;
        p1o[(cq*4+3)*P1_CS + base] = mx[t].w;
      }
    }
  }
}

// ---------------- K2 v6: conv2 + prelu + pool, REGISTER-PREFETCH staging ----------
// Per half: stage 36 KB global->LDS. v5 stalled all 8 waves on vmcnt at the
// staging store (VALUBusy 69% vs 16.1k-FMA floor). v6 issues half-1's global
// loads into pf[5] VGPRs BEFORE half-0's ~16k-cycle compute, so the commit
// after the barrier is a pure VGPR->LDS write. +20 VGPR (~96 total, under the
// (512,4) cap of 128 — R4/R10 spill law respected).
#define K2_LOADW(W, CI, KH) { \
  const float* wp_ = w2 + (((KH)*3)*32 + (CI))*64 + co0; \
  W[0] = *(const float4*)(wp_);            W[1] = *(const float4*)(wp_ + 4); \
  W[2] = *(const float4*)(wp_ + 2048);     W[3] = *(const float4*)(wp_ + 2052); \
  W[4] = *(const float4*)(wp_ + 4096);     W[5] = *(const float4*)(wp_ + 4100); }

#define K2_COMP(W, CIL, KH) { \
  const float* ip_ = &in_s[(CIL)*P1_CS + (rl+(KH))*P1_RS + j0]; \
  float s_[9]; \
  _Pragma("unroll") for (int d_ = 0; d_ < 9; d_++) s_[d_] = ip_[d_]; \
  _Pragma("unroll") for (int kw_ = 0; kw_ < 3; kw_++) { \
    _Pragma("unroll") for (int jj_ = 0; jj_ < 7; jj_++) { \
      fma4(acc[jj_][0], s_[jj_+kw_], W[kw_*2]); \
      fma4(acc[jj_][1], s_[jj_+kw_], W[kw_*2+1]); } } }

#define K2_STORE8(PJ, LO, HI) { \
  float* d_ = p2o + (size_t)co0*120 + pi*12 + (PJ); \
  float4 lo_ = (LO), hi_ = (HI); \
  d_[0]   = lo_.x; d_[120] = lo_.y; d_[240] = lo_.z; d_[360] = lo_.w; \
  d_[480] = hi_.x; d_[600] = hi_.y; d_[720] = hi_.z; d_[840] = hi_.w; }

#define K2_PREFETCH(H) { \
  _Pragma("unroll") for (int k_ = 0; k_ < 5; k_++) { \
    int idx_ = tid + k_*512; \
    if (idx_ < 2304) pf[k_] = *(const float4*)&p1o[(H)*9216 + idx_*4]; } }

#define K2_COMMIT() { \
  _Pragma("unroll") for (int k_ = 0; k_ < 5; k_++) { \
    int idx_ = tid + k_*512; \
    if (idx_ < 2304) *(float4*)&in_s[idx_*4] = pf[k_]; } }

#define K2_HALF(CB) { \
    float4 wA[6], wB[6]; \
    K2_LOADW(wA, (CB)+0, 0); \
    _Pragma("unroll 1") \
    for (int ci = 0; ci < 16; ci += 2) { \
      K2_LOADW(wB, (CB)+ci, 1); \
      K2_COMP(wA, ci, 0); \
      K2_LOADW(wA, (CB)+ci, 2); \
      K2_COMP(wB, ci, 1); \
      K2_LOADW(wB, (CB)+ci+1, 0); \
      K2_COMP(wA, ci, 2); \
      K2_LOADW(wA, (CB)+ci+1, 1); \
      K2_COMP(wB, ci+1, 0); \
      K2_LOADW(wB, (CB)+ci+1, 2); \
      K2_COMP(wA, ci+1, 1); \
      if (ci + 2 < 16) K2_LOADW(wA, (CB)+ci+2, 0); \
      K2_COMP(wB, ci+1, 2); \
    } }

__global__ __launch_bounds__(512, 4) void k2_conv2(
    const float* __restrict__ w2, const float* __restrict__ b2, const float* __restrict__ a2,
    const float* __restrict__ p1ws, float* __restrict__ p2ws)
{
  __shared__ float in_s[9216];            // 16 ch x 576 = 36864 B
  const int tid = threadIdx.x;
  const float* p1o = p1ws + (size_t)blockIdx.x * P1_SZ;
  float* p2o = p2ws + (size_t)blockIdx.x * 7680;

  const int wav = __builtin_amdgcn_readfirstlane(tid >> 6);
  const int lane = tid & 63;
  int jt = lane / 21;
  int rl = lane - jt * 21;
  if (lane == 63) { jt = 2; rl = 20; }    // tail lane: clamp, results discarded
  const int j0 = jt * 7;
  const int co0 = wav * 8;

  float4 bL = *(const float4*)&b2[co0];
  float4 bH = *(const float4*)&b2[co0+4];
  float4 aL = *(const float4*)&a2[co0];
  float4 aH = *(const float4*)&a2[co0+4];

  float4 acc[7][2];
#pragma unroll
  for (int jj = 0; jj < 7; jj++) { acc[jj][0] = bL; acc[jj][1] = bH; }

  float4 pf[5];
  // stage half 0
  K2_PREFETCH(0);
  K2_COMMIT();
  __syncthreads();

  // issue half-1 prefetch; loads fly during half-0 compute (~16k cyc)
  K2_PREFETCH(1);
  K2_HALF(0);

  __syncthreads();                         // all waves done reading half 0
  K2_COMMIT();                             // vmcnt long drained; pure LDS write
  __syncthreads();
  K2_HALF(16);

  // prelu
#pragma unroll
  for (int jj = 0; jj < 7; jj++) {
    acc[jj][0] = prelu4(acc[jj][0], aL);
    acc[jj][1] = prelu4(acc[jj][1], aH);
  }

  // vertical pool (rows rl, rl+1, rl+2) via shuffles, in place (lockstep-safe)
#pragma unroll
  for (int jj = 0; jj < 7; jj++) {
#pragma unroll
    for (int h = 0; h < 2; h++) {
      float4 v = acc[jj][h];
      float4 d1 = shfl4(v, lane + 1);
      float4 d2 = shfl4(v, lane + 2);
      acc[jj][h] = max34(v, d1, d2);
    }
  }
  // remote columns from next jt-group (lane+21): their jj=0 (cols j0+7) and jj=1
  float4 r0[2], r1[2];
#pragma unroll
  for (int h = 0; h < 2; h++) {
    r0[h] = shfl4(acc[0][h], lane + 21);
    r1[h] = shfl4(acc[1][h], lane + 21);
  }

  if (((rl & 1) == 0) && rl <= 18) {
    const int pi = rl >> 1;
    if (jt == 0) {
      K2_STORE8(0, max34(acc[0][0],acc[1][0],acc[2][0]), max34(acc[0][1],acc[1][1],acc[2][1]));
      K2_STORE8(1, max34(acc[2][0],acc[3][0],acc[4][0]), max34(acc[2][1],acc[3][1],acc[4][1]));
      K2_STORE8(2, max34(acc[4][0],acc[5][0],acc[6][0]), max34(acc[4][1],acc[5][1],acc[6][1]));
      K2_STORE8(3, max34(acc[6][0],r0[0],r1[0]),          max34(acc[6][1],r0[1],r1[1]));
    } else if (jt == 1) {
      K2_STORE8(4, max34(acc[1][0],acc[2][0],acc[3][0]), max34(acc[1][1],acc[2][1],acc[3][1]));
      K2_STORE8(5, max34(acc[3][0],acc[4][0],acc[5][0]), max34(acc[3][1],acc[4][1],acc[5][1]));
      K2_STORE8(6, max34(acc[5][0],acc[6][0],r0[0]),     max34(acc[5][1],acc[6][1],r0[1]));
    } else {
      K2_STORE8(7, max34(acc[0][0],acc[1][0],acc[2][0]), max34(acc[0][1],acc[1][1],acc[2][1]));
      K2_STORE8(8, max34(acc[2][0],acc[3][0],acc[4][0]), max34(acc[2][1],acc[3][1],acc[4][1]));
      K2_STORE8(9, max34(acc[4][0],acc[5][0],acc[6][0]), max34(acc[4][1],acc[5][1],acc[6][1]));
    }
  }
}

// ---------------- K34: conv3+pool then conv4 (merged; p3 in LDS) ------------------
#define K3_LOADW(W, CI, KH) { \
  const float* wp_ = w3 + (((KH)*3)*64 + (CI))*64 + co0; \
  W[0] = *(const float4*)(wp_);            W[1] = *(const float4*)(wp_ + 4); \
  W[2] = *(const float4*)(wp_ + 4096);     W[3] = *(const float4*)(wp_ + 4100); \
  W[4] = *(const float4*)(wp_ + 8192);     W[5] = *(const float4*)(wp_ + 8196); }

#define K3_COMP(W, CIL, KH) { \
  const float* ip_ = ibase + (CIL)*120 + (KH)*12; \
  float2 sA_ = *(const float2*)(ip_); \
  float2 sB_ = *(const float2*)(ip_ + 2); \
  float s_[4] = {sA_.x, sA_.y, sB_.x, sB_.y}; \
  _Pragma("unroll") for (int kw_ = 0; kw_ < 3; kw_++) { \
    _Pragma("unroll") for (int c_ = 0; c_ < 2; c_++) { \
      fma4(acc[c_][0], s_[c_+kw_], W[kw_*2]); \
      fma4(acc[c_][1], s_[c_+kw_], W[kw_*2+1]); } } }

__global__ __launch_bounds__(512) void k34_conv34(
    const float* __restrict__ w3, const float* __restrict__ b3, const float* __restrict__ a3,
    const float* __restrict__ w4, const float* __restrict__ b4, const float* __restrict__ a4,
    const float* __restrict__ p2ws, float* __restrict__ c4ws)
{
  __shared__ float in_s[7696];             // 2 boxes x 32ch x 120 (+8 skew)
  __shared__ float p3s[2*1032];            // 2 boxes x [64][4][4] (+8 skew)
  const int tid = threadIdx.x;
  const int bi0 = blockIdx.x * 2;
  const float* p2o = p2ws + (size_t)bi0 * 7680;

  const int wav = __builtin_amdgcn_readfirstlane(tid >> 6);
  const int lane = tid & 63;

  // ---- phase A: conv3 + prelu + pool(2,2) -> p3s ----
  {
    const int b  = lane >> 5;
    const int r  = (lane >> 2) & 7;
    const int cg = lane & 3;
    const int co0 = wav * 8;

    float4 bL = *(const float4*)&b3[co0];
    float4 bH = *(const float4*)&b3[co0+4];
    float4 aL = *(const float4*)&a3[co0];
    float4 aH = *(const float4*)&a3[co0+4];

    float4 acc[2][2];
    acc[0][0] = bL; acc[0][1] = bH; acc[1][0] = bL; acc[1][1] = bH;

    const float* ibase = &in_s[b*3848 + r*12 + cg*2];

#pragma unroll 1
    for (int h = 0; h < 2; h++) {
      __syncthreads();
      for (int i4 = tid; i4 < 1920; i4 += 512) {   // 2 x 3840 floats / 4
        int bb = (i4 >= 960) ? 1 : 0;
        int k = i4 - bb*960;
        *(float4*)&in_s[bb*3848 + k*4] = *(const float4*)&p2o[(size_t)bb*7680 + h*3840 + k*4];
      }
      __syncthreads();

      const int cb = h*32;
      float4 wA[6], wB[6];
      K3_LOADW(wA, cb+0, 0);
#pragma unroll 1
      for (int ci = 0; ci < 32; ci += 2) {
        K3_LOADW(wB, cb+ci, 1);
        K3_COMP(wA, ci, 0);
        K3_LOADW(wA, cb+ci, 2);
        K3_COMP(wB, ci, 1);
        K3_LOADW(wB, cb+ci+1, 0);
        K3_COMP(wA, ci, 2);
        K3_LOADW(wA, cb+ci+1, 1);
        K3_COMP(wB, ci+1, 0);
        K3_LOADW(wB, cb+ci+1, 2);
        K3_COMP(wA, ci+1, 1);
        if (ci + 2 < 32) K3_LOADW(wA, cb+ci+2, 0);
        K3_COMP(wB, ci+1, 2);
      }
    }

    float4 hm[2];
#pragma unroll
    for (int h = 0; h < 2; h++) {
      float4 p0 = prelu4(acc[0][h], h ? aH : aL);
      float4 p1 = prelu4(acc[1][h], h ? aH : aL);
      hm[h] = max4(p0, p1);
    }
    float4 o[2];
#pragma unroll
    for (int h = 0; h < 2; h++) {
      float4 d = shfl4(hm[h], lane + 4);
      o[h] = max4(hm[h], d);
    }
    if ((r & 1) == 0) {
      const int pi = r >> 1;
      float* d = &p3s[b*1032 + co0*16 + pi*4 + cg];
      d[0]   = o[0].x; d[16]  = o[0].y; d[32]  = o[0].z; d[48]  = o[0].w;
      d[64]  = o[1].x; d[80]  = o[1].y; d[96]  = o[1].z; d[112] = o[1].w;
    }
  }
  __syncthreads();

  // ---- phase B: conv4 + prelu -> c4 (global, NCHW-flat [128*9]) ----
  {
    const int bb  = wav >> 2;
    const int wv  = wav & 3;
    const int coq = lane >> 4;
    const int sp  = lane & 15;
    const bool act = sp < 9;
    const int sq = act ? sp : 8;
    const int r4 = sq / 3, cc4 = sq - 3*r4;
    const int co8 = wv*32 + coq*8;
    const float* base = &p3s[bb*1032 + r4*4 + cc4];
    float* c4o = c4ws + (size_t)(bi0+bb)*1152;

    float4 acc0 = *(const float4*)&b4[co8];
    float4 acc1 = *(const float4*)&b4[co8+4];
#pragma unroll 1
    for (int ci = 0; ci < 64; ci++) {
      const float* ip = base + ci*16;
      float i00 = ip[0], i01 = ip[1], i10 = ip[4], i11 = ip[5];
      const float* wp = w4 + ci*128 + co8;
      float4 W00a = *(const float4*)(wp);         float4 W00b = *(const float4*)(wp+4);
      float4 W01a = *(const float4*)(wp + 8192);  float4 W01b = *(const float4*)(wp+8196);
      float4 W10a = *(const float4*)(wp + 16384); float4 W10b = *(const float4*)(wp+16388);
      float4 W11a = *(const float4*)(wp + 24576); float4 W11b = *(const float4*)(wp+24580);
      fma4(acc0, i00, W00a); fma4(acc1, i00, W00b);
      fma4(acc0, i01, W01a); fma4(acc1, i01, W01b);
      fma4(acc0, i10, W10a); fma4(acc1, i10, W10b);
      fma4(acc0, i11, W11a); fma4(acc1, i11, W11b);
    }
    if (act) {
      float4 p0 = prelu4(acc0, *(const float4*)&a4[co8]);
      float4 p1 = prelu4(acc1, *(const float4*)&a4[co8+4]);
      float* d = c4o + (size_t)co8*9 + sp;
      d[0]  = p0.x; d[9]  = p0.y; d[18] = p0.z; d[27] = p0.w;
      d[36] = p1.x; d[45] = p1.y; d[54] = p1.z; d[63] = p1.w;
    }
  }
}

// ---------------- K5 v3: coalesced-weight fc5 + oi x2 unroll, fc6, softmax --------
__global__ __launch_bounds__(512) void k5_fc(
    const float* __restrict__ fc5w, const float* __restrict__ fc5b, const float* __restrict__ a5,
    const float* __restrict__ w6a, const float* __restrict__ b6a,
    const float* __restrict__ w6b, const float* __restrict__ b6b,
    const float* __restrict__ bboxes, const float* __restrict__ c4ws,
    float* __restrict__ ws_scores, float* __restrict__ ws_boxes, int box0)
{
  __shared__ float c4s[8*1152];            // 36.9 KB
  __shared__ float hs[8*256];
  __shared__ float l6[8][6];
  const int tid = threadIdx.x;
  const int lb0 = blockIdx.x * 8;          // chunk-local first box
  for (int idx4 = tid; idx4 < 2304; idx4 += 512)
    *(float4*)&c4s[idx4*4] = *(const float4*)&c4ws[(size_t)lb0*1152 + idx4*4];
  __syncthreads();

  const int wav = __builtin_amdgcn_readfirstlane(tid >> 6);  // 0..7
  const int lane = tid & 63;
  const int half = lane >> 5;
  const int l32  = lane & 31;
  const int b    = 2*(wav & 3) + half;     // box within block (0..7)
  const int ob   = (wav >> 2) * 128;       // o-range
  const float* cb = &c4s[b*1152 + l32*4];

#pragma unroll 1
  for (int oi = 0; oi < 128; oi += 2) {
    const int o0 = ob + oi, o1 = ob + oi + 1;
    const float* wr0 = fc5w + (size_t)o0*1152 + l32*4;
    const float* wr1 = wr0 + 1152;
    float ac0 = 0.f, ac1 = 0.f;
#pragma unroll
    for (int j = 0; j < 9; j++) {
      float4 cv = *(const float4*)(cb + j*128);
      float4 w0 = *(const float4*)(wr0 + j*128);
      float4 w1v = *(const float4*)(wr1 + j*128);
      ac0 = fmaf(cv.x, w0.x, ac0);  ac1 = fmaf(cv.x, w1v.x, ac1);
      ac0 = fmaf(cv.y, w0.y, ac0);  ac1 = fmaf(cv.y, w1v.y, ac1);
      ac0 = fmaf(cv.z, w0.z, ac0);  ac1 = fmaf(cv.z, w1v.z, ac1);
      ac0 = fmaf(cv.w, w0.w, ac0);  ac1 = fmaf(cv.w, w1v.w, ac1);
    }
    ac0 += __shfl_down(ac0, 16, 32);  ac1 += __shfl_down(ac1, 16, 32);
    ac0 += __shfl_down(ac0,  8, 32);  ac1 += __shfl_down(ac1,  8, 32);
    ac0 += __shfl_down(ac0,  4, 32);  ac1 += __shfl_down(ac1,  4, 32);
    ac0 += __shfl_down(ac0,  2, 32);  ac1 += __shfl_down(ac1,  2, 32);
    ac0 += __shfl_down(ac0,  1, 32);  ac1 += __shfl_down(ac1,  1, 32);
    if (l32 == 0) {
      float h0 = ac0 + fc5b[o0];
      h0 = h0 >= 0.f ? h0 : a5[o0]*h0;
      hs[b*256 + o0] = h0;
      float h1 = ac1 + fc5b[o1];
      h1 = h1 >= 0.f ? h1 : a5[o1]*h1;
      hs[b*256 + o1] = h1;
    }
  }
  __syncthreads();

  if (tid < 48) {
    int bb = tid / 6, oi = tid % 6;
    const float* w = (oi < 2) ? &w6a[oi*256] : &w6b[(oi-2)*256];
    float d = (oi < 2) ? b6a[oi] : b6b[oi-2];
    const float* hh = &hs[bb*256];
    for (int k = 0; k < 256; k++) d += hh[k]*w[k];
    l6[bb][oi] = d;
  }
  __syncthreads();
  if (tid < 8) {
    int n = box0 + lb0 + tid;
    float l0 = l6[tid][0], l1 = l6[tid][1];
    float m = fmaxf(l0, l1);
    float e0 = expf(l0-m), e1 = expf(l1-m);
    float score = e1/(e0+e1);
    float r0 = l6[tid][2], r1 = l6[tid][3], r2 = l6[tid][4], r3 = l6[tid][5];
    float f0 = bboxes[n*4+0], f1 = bboxes[n*4+1], f2 = bboxes[n*4+2], f3 = bboxes[n*4+3];
    float bx1 = fmaxf(f0, 0.f), by1 = fmaxf(f1, 0.f);
    float bx2 = fminf(f2, 1024.f), by2 = fminf(f3, 1024.f);
    float w_ = bx2-bx1, h_ = by2-by1;
    ws_scores[n] = score;
    float4 ob2 = make_float4(bx1 + r0*w_, by1 + r1*h_, bx2 + r2*w_, by2 + r3*h_);
    *(float4*)&ws_boxes[n*4] = ob2;
  }
}

// ---------------- K6a: bitonic sort (score desc, idx asc), nv, sorted boxes -------
__global__ __launch_bounds__(1024) void k6a_sort(
    const float* __restrict__ ws_scores, const float* __restrict__ ws_boxes,
    int* __restrict__ sidx_ws, float* __restrict__ sbox_ws,
    float* __restrict__ area_ws, int* __restrict__ nv_ws)
{
  __shared__ float skey[2048];
  __shared__ int   sidx[2048];
  const int tid = threadIdx.x;
  for (int i = tid; i < 2048; i += 1024) {
    float s = ws_scores[i];
    skey[i] = (s >= 0.5f) ? s : -INFINITY;
    sidx[i] = i;
  }
  __syncthreads();
  for (int k = 2; k <= 2048; k <<= 1) {
    for (int j = k >> 1; j > 0; j >>= 1) {
      for (int i = tid; i < 2048; i += 1024) {
        int ixj = i ^ j;
        if (ixj > i) {
          float a = skey[i], b = skey[ixj];
          int ia = sidx[i], ib = sidx[ixj];
          bool up = ((i & k) == 0);
          bool aAfterB = (a < b) || (a == b && ia > ib);
          if (up ? aAfterB : !aAfterB) {
            skey[i] = b; skey[ixj] = a; sidx[i] = ib; sidx[ixj] = ia;
          }
        }
      }
      __syncthreads();
    }
  }
  if (tid == 0) nv_ws[0] = 2048;
  __syncthreads();
  for (int i = tid; i < 2048; i += 1024) {
    if (skey[i] == -INFINITY && (i == 0 || skey[i-1] != -INFINITY)) nv_ws[0] = i;
    int n = sidx[i];
    sidx_ws[i] = n;
    float4 b = *(const float4*)&ws_boxes[n*4];
    *(float4*)&sbox_ws[i*4] = b;
    area_ws[i] = (b.z-b.x)*(b.w-b.y);
  }
}

// ---------------- K6b: suppression bitmask matrix M[2048][32] ---------------------
__global__ __launch_bounds__(256) void k6b_iou(
    const int* __restrict__ nv_ws, const float* __restrict__ sbox_ws,
    const float* __restrict__ area_ws, unsigned long long* __restrict__ M)
{
  const int nv = nv_ws[0];
  int gt = blockIdx.x*256 + threadIdx.x;
  for (int w = gt; w < 2048*32; w += 128*256) {
    int i = w >> 5, wg = w & 31;
    if (i >= nv) continue;
    float4 bi = *(const float4*)&sbox_ws[i*4];
    float ai = area_ws[i];
    unsigned long long m = 0;
    int jbase = wg*64;
    if (jbase + 63 > i) {
      for (int jj = 0; jj < 64; jj++) {
        int j = jbase + jj;
        if (j <= i) continue;
        float4 bj = *(const float4*)&sbox_ws[j*4];
        float xx1 = fmaxf(bi.x, bj.x), yy1 = fmaxf(bi.y, bj.y);
        float xx2 = fminf(bi.z, bj.z), yy2 = fminf(bi.w, bj.w);
        float iw = fmaxf(xx2-xx1, 0.f), ih = fmaxf(yy2-yy1, 0.f);
        float inter = iw*ih;
        float iou = inter / (ai + area_ws[j] - inter + 1e-12f);
        if (iou > 0.5f) m |= (1ull << jj);
      }
    }
    M[w] = m;
  }
}

// ---------------- K6c: greedy scan (wave 0) + masked scatter to output ------------
__global__ __launch_bounds__(1024) void k6c_scan(
    const int* __restrict__ nv_ws, const int* __restrict__ sidx_ws,
    const float* __restrict__ sbox_ws, const unsigned long long* __restrict__ M,
    float* __restrict__ out)
{
  __shared__ unsigned long long Msh[128*32];
  __shared__ unsigned long long rem_sh[32];
  const int tid = threadIdx.x;
  const int nv = nv_ws[0];
  unsigned long long rem = 0;

  for (int c0 = 0; c0 < 2048; c0 += 128) {
    if (c0 >= nv) break;
    for (int w = tid; w < 128*32; w += 1024) {
      int i = c0 + (w >> 5);
      if (i < nv) Msh[w] = M[(size_t)i*32 + (w & 31)];
    }
    __syncthreads();
    if (tid < 64) {
      int iend = c0 + 128; if (iend > nv) iend = nv;
      for (int i = c0; i < iend; i += 4) {
        unsigned long long m0=0, m1=0, m2=0, m3=0;
        int base = (i - c0) << 5;
        if (tid < 32) {
          m0 = Msh[base + tid];
          if (i+1 < iend) m1 = Msh[base + 32 + tid];
          if (i+2 < iend) m2 = Msh[base + 64 + tid];
          if (i+3 < iend) m3 = Msh[base + 96 + tid];
        }
        unsigned long long rw = __shfl(rem, (i >> 6), 64);
        if (!((rw >> (i & 63)) & 1ull)) rem |= m0;
        if (i+1 < iend) {
          rw = __shfl(rem, ((i+1) >> 6), 64);
          if (!((rw >> ((i+1) & 63)) & 1ull)) rem |= m1;
        }
        if (i+2 < iend) {
          rw = __shfl(rem, ((i+2) >> 6), 64);
          if (!((rw >> ((i+2) & 63)) & 1ull)) rem |= m2;
        }
        if (i+3 < iend) {
          rw = __shfl(rem, ((i+3) >> 6), 64);
          if (!((rw >> ((i+3) & 63)) & 1ull)) rem |= m3;
        }
      }
    }
    __syncthreads();
  }
  if (tid < 32) rem_sh[tid] = rem;
  __syncthreads();
  for (int i = tid; i < 2048; i += 1024) {
    bool keep = (i < nv) && !((rem_sh[i >> 6] >> (i & 63)) & 1ull);
    int n = sidx_ws[i];
    float4 b = *(const float4*)&sbox_ws[i*4];
    float4 o = keep ? b : make_float4(0.f,0.f,0.f,0.f);
    *(float4*)&out[n*4] = o;
  }
}

// ---------------- host ------------------------------------------------------------
extern "C" void kernel_launch(void* const* d_in, const int* in_sizes, int n_in,
                              void* d_out, int out_size, void* d_ws, size_t ws_size,
                              hipStream_t stream)
{
  const float* bboxes = (const float*)d_in[0];
  const float* image  = (const float*)d_in[1];
  const float* w1 = (const float*)d_in[2];  const float* b1 = (const float*)d_in[3];  const float* a1 = (const float*)d_in[4];
  const float* w2 = (const float*)d_in[5];  const float* b2 = (const float*)d_in[6];  const float* a2 = (const float*)d_in[7];
  const float* w3 = (const float*)d_in[8];  const float* b3 = (const float*)d_in[9];  const float* a3 = (const float*)d_in[10];
  const float* w4 = (const float*)d_in[11]; const float* b4 = (const float*)d_in[12]; const float* a4 = (const float*)d_in[13];
  const float* fc5w = (const float*)d_in[14]; const float* fc5b = (const float*)d_in[15]; const float* a5 = (const float*)d_in[16];
  const float* w6a = (const float*)d_in[17]; const float* b6a = (const float*)d_in[18];
  const float* w6b = (const float*)d_in[19]; const float* b6b = (const float*)d_in[20];
  float* out = (float*)d_out;

  char* ws = (char*)d_ws;
  size_t off = 0;
  auto alloc = [&](size_t bytes) -> size_t {
    size_t p = off; off += (bytes + 255) & ~(size_t)255; return p;
  };
  size_t o_scores = alloc(NBOX*4);
  size_t o_boxes  = alloc(NBOX*16);
  size_t o_sidx   = alloc(NBOX*4);
  size_t o_sbox   = alloc(NBOX*16);
  size_t o_area   = alloc(NBOX*4);
  size_t o_nv     = alloc(256);
  size_t o_M      = alloc((size_t)NBOX*32*8);
  size_t fixed = off;
  const size_t perbox = (size_t)(P1_SZ + 7680 + 1152) * 4;  // 109,056 B (p3 in LDS)

  int B = NBOX;
  if (fixed + (size_t)B*perbox > ws_size) {
    size_t avail = ws_size > fixed ? ws_size - fixed : 0;
    B = (int)(avail / perbox);
    B &= ~7;                 // multiple of 8 for K5 grid / K34 pairing
    if (B < 8) B = 8;
    if (B > NBOX) B = NBOX;
  }
  size_t o_p1 = alloc((size_t)B*P1_SZ*4);
  size_t o_p2 = alloc((size_t)B*7680*4);
  size_t o_c4 = alloc((size_t)B*1152*4);

  float* ws_scores = (float*)(ws + o_scores);
  float* ws_boxes  = (float*)(ws + o_boxes);
  int*   sidxp     = (int*)(ws + o_sidx);
  float* sboxp     = (float*)(ws + o_sbox);
  float* areap     = (float*)(ws + o_area);
  int*   nvp       = (int*)(ws + o_nv);
  unsigned long long* Mp = (unsigned long long*)(ws + o_M);
  float* p1p = (float*)(ws + o_p1);
  float* p2p = (float*)(ws + o_p2);
  float* c4p = (float*)(ws + o_c4);

  for (int c0 = 0; c0 < NBOX; c0 += B) {
    int Bc = NBOX - c0; if (Bc > B) Bc = B;
    k1_crop_conv1<<<Bc, 256, 0, stream>>>(bboxes, image, w1, b1, a1, p1p, c0);
    k2_conv2<<<Bc, 512, 0, stream>>>(w2, b2, a2, p1p, p2p);
    k34_conv34<<<Bc/2, 512, 0, stream>>>(w3, b3, a3, w4, b4, a4, p2p, c4p);
    k5_fc<<<Bc/8, 512, 0, stream>>>(fc5w, fc5b, a5, w6a, b6a, w6b, b6b,
                                    bboxes, c4p, ws_scores, ws_boxes, c0);
  }
  k6a_sort<<<1, 1024, 0, stream>>>(ws_scores, ws_boxes, sidxp, sboxp, areap, nvp);
  k6b_iou<<<128, 256, 0, stream>>>(nvp, sboxp, areap, Mp);
  k6c_scan<<<1, 1024, 0, stream>>>(nvp, sidxp, sboxp, Mp, out);
}

// Round 13
// 1542.826 us; speedup vs baseline: 1.0467x; 1.0467x over previous
//
#include <hip/hip_runtime.h>
#include <math.h>
#include <stdint.h>

#define NBOX 2048

// p1 layout: [32 ch][23 rows][25 cols (23 valid + 2 pad)], ch stride 576 floats.
// stride 25 (odd) => conflict-free-ish LDS reads in K2 (24 caused 6-way, 141M cyc).
#define P1_RS 25
#define P1_CS 576
#define P1_SZ 18432

__device__ __forceinline__ void fma4(float4& a, float s, const float4& w) {
  a.x = fmaf(s, w.x, a.x); a.y = fmaf(s, w.y, a.y);
  a.z = fmaf(s, w.z, a.z); a.w = fmaf(s, w.w, a.w);
}
__device__ __forceinline__ float4 max4(float4 a, float4 b) {
  return make_float4(fmaxf(a.x,b.x), fmaxf(a.y,b.y), fmaxf(a.z,b.z), fmaxf(a.w,b.w));
}
__device__ __forceinline__ float4 max34(float4 a, float4 b, float4 c) {
  return max4(max4(a, b), c);
}
__device__ __forceinline__ float4 prelu4(float4 v, float4 a) {
  float4 r;
  r.x = v.x >= 0.f ? v.x : a.x*v.x;
  r.y = v.y >= 0.f ? v.y : a.y*v.y;
  r.z = v.z >= 0.f ? v.z : a.z*v.z;
  r.w = v.w >= 0.f ? v.w : a.w*v.w;
  return r;
}
__device__ __forceinline__ float4 shfl4(float4 v, int src) {
  float4 r;
  r.x = __shfl(v.x, src, 64); r.y = __shfl(v.y, src, 64);
  r.z = __shfl(v.z, src, 64); r.w = __shfl(v.w, src, 64);
  return r;
}

// ---------------- K1 (R5-proven, 256 threads): crop + conv1 + prelu + pool --------
// SESSION LAW: K1's per-slot live state (~100+ VGPRs) spills at 512 threads
// (R10: 2.5 GB scratch writes, 2.3x regression). Keep 256 threads.
__global__ __launch_bounds__(256) void k1_crop_conv1(
    const float* __restrict__ bboxes, const float* __restrict__ image,
    const float* __restrict__ w1, const float* __restrict__ b1, const float* __restrict__ a1,
    float* __restrict__ p1ws, int box0)
{
  __shared__ float crop[48*48*3];
  const int tid = threadIdx.x;
  const int n = box0 + blockIdx.x;

  float f0 = bboxes[n*4+0], f1 = bboxes[n*4+1], f2 = bboxes[n*4+2], f3 = bboxes[n*4+3];
  float bx1 = fmaxf(f0, 0.f), by1 = fmaxf(f1, 0.f);
  float bx2 = fminf(f2, 1024.f), by2 = fminf(f3, 1024.f);
  int ix1 = (int)bx1, iy1 = (int)by1, ix2 = (int)bx2, iy2 = (int)by2;
  int cw = ix2 - ix1; if (cw < 1) cw = 1;
  int ch = iy2 - iy1; if (ch < 1) ch = 1;

  for (int idx = tid; idx < 6912; idx += 256) {
    int c = idx % 3; int t = idx / 3; int j = t % 48; int i = t / 48;
    int gx = ix1 + (j * cw) / 48;
    int gy = iy1 + (i * ch) / 48;
    float v = image[(gy*1024 + gx)*3 + c];
    crop[idx] = (v - 127.5f) * 0.0078125f;
  }
  __syncthreads();

  float* p1o = p1ws + (size_t)blockIdx.x * P1_SZ;

  for (int slot = tid; slot < 1104; slot += 256) {  // 23 * 6 * 8
    int cq = slot & 7;
    int t2 = slot >> 3;
    int pjq = t2 % 6;
    int pi  = t2 / 6;
    int pj0 = pjq * 4;
    int c0 = 2*pj0 - 1;
    float4 bias  = *(const float4*)&b1[cq*4];
    float4 alpha = *(const float4*)&a1[cq*4];
    float4 mx[4];
#pragma unroll
    for (int t = 0; t < 4; t++) mx[t] = make_float4(-3.0e38f,-3.0e38f,-3.0e38f,-3.0e38f);

#pragma unroll
    for (int dr = 0; dr < 3; dr++) {
      int r = 2*pi - 1 + dr;
      if (r < 0 || r > 45) continue;
      float4 acc[9];
#pragma unroll
      for (int c = 0; c < 9; c++) acc[c] = bias;
#pragma unroll
      for (int kh = 0; kh < 3; kh++) {
        int row = r + kh;
        float s[33];
#pragma unroll
        for (int d = 0; d < 11; d++) {
          int cc = c0 + d; cc = cc < 0 ? 0 : (cc > 47 ? 47 : cc);
          int base = row*144 + cc*3;
          s[d*3+0] = crop[base+0];
          s[d*3+1] = crop[base+1];
          s[d*3+2] = crop[base+2];
        }
#pragma unroll
        for (int kw = 0; kw < 3; kw++) {
#pragma unroll
          for (int ci = 0; ci < 3; ci++) {
            float4 w = *(const float4*)&w1[((kh*3+kw)*3+ci)*32 + cq*4];
#pragma unroll
            for (int c = 0; c < 9; c++) fma4(acc[c], s[(c+kw)*3+ci], w);
          }
        }
      }
#pragma unroll
      for (int c = 0; c < 9; c++) {
        int cabs = c0 + c;
        if (cabs < 0 || cabs > 45) continue;
        float4 pv = prelu4(acc[c], alpha);
#pragma unroll
        for (int t = 0; t < 4; t++) {
          if (c >= 2*t && c <= 2*t+2) mx[t] = max4(mx[t], pv);
        }
      }
    }
#pragma unroll
    for (int t = 0; t < 4; t++) {
      int pj = pj0 + t;
      if (pj < 23) {
        int base = pi*P1_RS + pj;
        p1o[(cq*4+0)*P1_CS + base] = mx[t].x;
        p1o[(cq*4+1)*P1_CS + base] = mx[t].y;
        p1o[(cq*4+2)*P1_CS + base] = mx[t].z;
        p1o[(cq*4+3)*P1_CS + base] = mx[t].w;
      }
    }
  }
}

// ---------------- K2 v5 (R5/R9-proven): conv2 + prelu + pool(3,2,0) -> p2T --------
// SESSION LAWS: weights stay s_load/SGPR (per-lane global_load regressed, R6);
// launch_bounds stays (512,4) ((512,8) spilled acc, R4); staging stays the
// simple sync loop (VGPR register-prefetch was spilled to scratch by the
// compiler's occupancy heuristic, R12: WRITE 265->402 MB, +50 us).
#define K2_LOADW(W, CI, KH) { \
  const float* wp_ = w2 + (((KH)*3)*32 + (CI))*64 + co0; \
  W[0] = *(const float4*)(wp_);            W[1] = *(const float4*)(wp_ + 4); \
  W[2] = *(const float4*)(wp_ + 2048);     W[3] = *(const float4*)(wp_ + 2052); \
  W[4] = *(const float4*)(wp_ + 4096);     W[5] = *(const float4*)(wp_ + 4100); }

#define K2_COMP(W, CIL, KH) { \
  const float* ip_ = &in_s[(CIL)*P1_CS + (rl+(KH))*P1_RS + j0]; \
  float s_[9]; \
  _Pragma("unroll") for (int d_ = 0; d_ < 9; d_++) s_[d_] = ip_[d_]; \
  _Pragma("unroll") for (int kw_ = 0; kw_ < 3; kw_++) { \
    _Pragma("unroll") for (int jj_ = 0; jj_ < 7; jj_++) { \
      fma4(acc[jj_][0], s_[jj_+kw_], W[kw_*2]); \
      fma4(acc[jj_][1], s_[jj_+kw_], W[kw_*2+1]); } } }

#define K2_STORE8(PJ, LO, HI) { \
  float* d_ = p2o + (size_t)co0*120 + pi*12 + (PJ); \
  float4 lo_ = (LO), hi_ = (HI); \
  d_[0]   = lo_.x; d_[120] = lo_.y; d_[240] = lo_.z; d_[360] = lo_.w; \
  d_[480] = hi_.x; d_[600] = hi_.y; d_[720] = hi_.z; d_[840] = hi_.w; }

__global__ __launch_bounds__(512, 4) void k2_conv2(
    const float* __restrict__ w2, const float* __restrict__ b2, const float* __restrict__ a2,
    const float* __restrict__ p1ws, float* __restrict__ p2ws)
{
  __shared__ float in_s[9216];            // 16 ch x 576 = 36864 B
  const int tid = threadIdx.x;
  const float* p1o = p1ws + (size_t)blockIdx.x * P1_SZ;
  float* p2o = p2ws + (size_t)blockIdx.x * 7680;

  const int wav = __builtin_amdgcn_readfirstlane(tid >> 6);
  const int lane = tid & 63;
  int jt = lane / 21;
  int rl = lane - jt * 21;
  if (lane == 63) { jt = 2; rl = 20; }    // tail lane: clamp, results discarded
  const int j0 = jt * 7;
  const int co0 = wav * 8;

  float4 bL = *(const float4*)&b2[co0];
  float4 bH = *(const float4*)&b2[co0+4];
  float4 aL = *(const float4*)&a2[co0];
  float4 aH = *(const float4*)&a2[co0+4];

  float4 acc[7][2];
#pragma unroll
  for (int jj = 0; jj < 7; jj++) { acc[jj][0] = bL; acc[jj][1] = bH; }

#pragma unroll 1
  for (int h = 0; h < 2; h++) {
    __syncthreads();                       // protect previous half's reads
    for (int i4 = tid; i4 < 2304; i4 += 512)
      *(float4*)&in_s[i4*4] = *(const float4*)&p1o[h*9216 + i4*4];
    __syncthreads();

    const int cb = h*16;                   // global channel base for weights
    float4 wA[6], wB[6];
    K2_LOADW(wA, cb+0, 0);
#pragma unroll 1
    for (int ci = 0; ci < 16; ci += 2) {
      K2_LOADW(wB, cb+ci, 1);
      K2_COMP(wA, ci, 0);
      K2_LOADW(wA, cb+ci, 2);
      K2_COMP(wB, ci, 1);
      K2_LOADW(wB, cb+ci+1, 0);
      K2_COMP(wA, ci, 2);
      K2_LOADW(wA, cb+ci+1, 1);
      K2_COMP(wB, ci+1, 0);
      K2_LOADW(wB, cb+ci+1, 2);
      K2_COMP(wA, ci+1, 1);
      if (ci + 2 < 16) K2_LOADW(wA, cb+ci+2, 0);
      K2_COMP(wB, ci+1, 2);
    }
  }

  // prelu
#pragma unroll
  for (int jj = 0; jj < 7; jj++) {
    acc[jj][0] = prelu4(acc[jj][0], aL);
    acc[jj][1] = prelu4(acc[jj][1], aH);
  }

  // vertical pool (rows rl, rl+1, rl+2) via shuffles, in place (lockstep-safe)
#pragma unroll
  for (int jj = 0; jj < 7; jj++) {
#pragma unroll
    for (int h = 0; h < 2; h++) {
      float4 v = acc[jj][h];
      float4 d1 = shfl4(v, lane + 1);
      float4 d2 = shfl4(v, lane + 2);
      acc[jj][h] = max34(v, d1, d2);
    }
  }
  // remote columns from next jt-group (lane+21): their jj=0 (cols j0+7) and jj=1
  float4 r0[2], r1[2];
#pragma unroll
  for (int h = 0; h < 2; h++) {
    r0[h] = shfl4(acc[0][h], lane + 21);
    r1[h] = shfl4(acc[1][h], lane + 21);
  }

  if (((rl & 1) == 0) && rl <= 18) {
    const int pi = rl >> 1;
    if (jt == 0) {
      K2_STORE8(0, max34(acc[0][0],acc[1][0],acc[2][0]), max34(acc[0][1],acc[1][1],acc[2][1]));
      K2_STORE8(1, max34(acc[2][0],acc[3][0],acc[4][0]), max34(acc[2][1],acc[3][1],acc[4][1]));
      K2_STORE8(2, max34(acc[4][0],acc[5][0],acc[6][0]), max34(acc[4][1],acc[5][1],acc[6][1]));
      K2_STORE8(3, max34(acc[6][0],r0[0],r1[0]),          max34(acc[6][1],r0[1],r1[1]));
    } else if (jt == 1) {
      K2_STORE8(4, max34(acc[1][0],acc[2][0],acc[3][0]), max34(acc[1][1],acc[2][1],acc[3][1]));
      K2_STORE8(5, max34(acc[3][0],acc[4][0],acc[5][0]), max34(acc[3][1],acc[4][1],acc[5][1]));
      K2_STORE8(6, max34(acc[5][0],acc[6][0],r0[0]),     max34(acc[5][1],acc[6][1],r0[1]));
    } else {
      K2_STORE8(7, max34(acc[0][0],acc[1][0],acc[2][0]), max34(acc[0][1],acc[1][1],acc[2][1]));
      K2_STORE8(8, max34(acc[2][0],acc[3][0],acc[4][0]), max34(acc[2][1],acc[3][1],acc[4][1]));
      K2_STORE8(9, max34(acc[4][0],acc[5][0],acc[6][0]), max34(acc[4][1],acc[5][1],acc[6][1]));
    }
  }
}

// ---------------- K3 v4 (R5/R9-proven): conv3 + prelu + pool(2,2) -> p3T ----------
#define K3_LOADW(W, CI, KH) { \
  const float* wp_ = w3 + (((KH)*3)*64 + (CI))*64 + co0; \
  W[0] = *(const float4*)(wp_);            W[1] = *(const float4*)(wp_ + 4); \
  W[2] = *(const float4*)(wp_ + 4096);     W[3] = *(const float4*)(wp_ + 4100); \
  W[4] = *(const float4*)(wp_ + 8192);     W[5] = *(const float4*)(wp_ + 8196); }

#define K3_COMP(W, CIL, KH) { \
  const float* ip_ = ibase + (CIL)*120 + (KH)*12; \
  float2 sA_ = *(const float2*)(ip_); \
  float2 sB_ = *(const float2*)(ip_ + 2); \
  float s_[4] = {sA_.x, sA_.y, sB_.x, sB_.y}; \
  _Pragma("unroll") for (int kw_ = 0; kw_ < 3; kw_++) { \
    _Pragma("unroll") for (int c_ = 0; c_ < 2; c_++) { \
      fma4(acc[c_][0], s_[c_+kw_], W[kw_*2]); \
      fma4(acc[c_][1], s_[c_+kw_], W[kw_*2+1]); } } }

__global__ __launch_bounds__(512, 4) void k3_conv3(
    const float* __restrict__ w3, const float* __restrict__ b3, const float* __restrict__ a3,
    const float* __restrict__ p2ws, float* __restrict__ p3ws)
{
  __shared__ float in_s[7696];             // 2 boxes x 32ch x 120 (+8 skew)
  const int tid = threadIdx.x;
  const float* p2o = p2ws + (size_t)(blockIdx.x*2) * 7680;
  float* p3o0 = p3ws + (size_t)(blockIdx.x*2) * 1024;

  const int wav = __builtin_amdgcn_readfirstlane(tid >> 6);
  const int lane = tid & 63;
  const int b  = lane >> 5;
  const int r  = (lane >> 2) & 7;
  const int cg = lane & 3;
  const int co0 = wav * 8;

  float4 bL = *(const float4*)&b3[co0];
  float4 bH = *(const float4*)&b3[co0+4];
  float4 aL = *(const float4*)&a3[co0];
  float4 aH = *(const float4*)&a3[co0+4];

  float4 acc[2][2];
  acc[0][0] = bL; acc[0][1] = bH; acc[1][0] = bL; acc[1][1] = bH;

  const float* ibase = &in_s[b*3848 + r*12 + cg*2];

#pragma unroll 1
  for (int h = 0; h < 2; h++) {
    __syncthreads();
    for (int i4 = tid; i4 < 1920; i4 += 512) {   // 2 x 3840 floats / 4
      int bb = (i4 >= 960) ? 1 : 0;
      int k = i4 - bb*960;
      *(float4*)&in_s[bb*3848 + k*4] = *(const float4*)&p2o[(size_t)bb*7680 + h*3840 + k*4];
    }
    __syncthreads();

    const int cb = h*32;
    float4 wA[6], wB[6];
    K3_LOADW(wA, cb+0, 0);
#pragma unroll 1
    for (int ci = 0; ci < 32; ci += 2) {
      K3_LOADW(wB, cb+ci, 1);
      K3_COMP(wA, ci, 0);
      K3_LOADW(wA, cb+ci, 2);
      K3_COMP(wB, ci, 1);
      K3_LOADW(wB, cb+ci+1, 0);
      K3_COMP(wA, ci, 2);
      K3_LOADW(wA, cb+ci+1, 1);
      K3_COMP(wB, ci+1, 0);
      K3_LOADW(wB, cb+ci+1, 2);
      K3_COMP(wA, ci+1, 1);
      if (ci + 2 < 32) K3_LOADW(wA, cb+ci+2, 0);
      K3_COMP(wB, ci+1, 2);
    }
  }

  // prelu + horizontal (in-thread) pool
  float4 hm[2];
#pragma unroll
  for (int h = 0; h < 2; h++) {
    float4 p0 = prelu4(acc[0][h], h ? aH : aL);
    float4 p1 = prelu4(acc[1][h], h ? aH : aL);
    hm[h] = max4(p0, p1);
  }
  // vertical pool via shuffle (+4 lanes = next row, same box/colpair)
  float4 o[2];
#pragma unroll
  for (int h = 0; h < 2; h++) {
    float4 d = shfl4(hm[h], lane + 4);
    o[h] = max4(hm[h], d);
  }
  if ((r & 1) == 0) {
    const int pi = r >> 1;
    float* d = p3o0 + b*1024 + (size_t)co0*16 + pi*4 + cg;
    d[0]   = o[0].x; d[16]  = o[0].y; d[32]  = o[0].z; d[48]  = o[0].w;
    d[64]  = o[1].x; d[80]  = o[1].y; d[96]  = o[1].z; d[112] = o[1].w;
  }
}

// ---------------- K4 v2 (R5/R9-proven): conv4 + prelu -> c4 flat [128*9] ----------
#define K4_LOADW(W, CI) { \
  const float* wp_ = w4 + (CI)*128 + co0; \
  W[0] = *(const float4*)(wp_);           W[1] = *(const float4*)(wp_ + 4); \
  W[2] = *(const float4*)(wp_ + 8192);    W[3] = *(const float4*)(wp_ + 8196); \
  W[4] = *(const float4*)(wp_ + 16384);   W[5] = *(const float4*)(wp_ + 16388); \
  W[6] = *(const float4*)(wp_ + 24576);   W[7] = *(const float4*)(wp_ + 24580); }

#define K4_COMP(W, CI) { \
  const float* ip_ = base + (CI)*16; \
  float i00 = ip_[0], i01 = ip_[1], i10 = ip_[4], i11 = ip_[5]; \
  fma4(acc0, i00, W[0]); fma4(acc1, i00, W[1]); \
  fma4(acc0, i01, W[2]); fma4(acc1, i01, W[3]); \
  fma4(acc0, i10, W[4]); fma4(acc1, i10, W[5]); \
  fma4(acc0, i11, W[6]); fma4(acc1, i11, W[7]); }

__global__ __launch_bounds__(512) void k4_conv4(
    const float* __restrict__ w4, const float* __restrict__ b4, const float* __restrict__ a4,
    const float* __restrict__ p3ws, float* __restrict__ c4ws)
{
  __shared__ float p3s[4*1032];            // 4 boxes x 1024 (+8 skew)
  const int tid = threadIdx.x;
  const int bi0 = blockIdx.x * 4;

  for (int i4 = tid; i4 < 1024; i4 += 512) {
    int bb = i4 >> 8, k = i4 & 255;
    *(float4*)&p3s[bb*1032 + k*4] = *(const float4*)&p3ws[(size_t)(bi0+bb)*1024 + k*4];
  }
  __syncthreads();

  const int wav = __builtin_amdgcn_readfirstlane(tid >> 6);
  const int lane = tid & 63;
  const int bx = lane >> 4;
  const int sp = lane & 15;
  const bool act = sp < 9;
  const int sq = act ? sp : 8;
  const int r = sq / 3, c = sq - 3*r;
  const float* base = &p3s[bx*1032 + r*4 + c];
  float* c4o = c4ws + (size_t)(bi0+bx)*1152;

#pragma unroll 1
  for (int p = 0; p < 2; p++) {
    const int co0 = p*64 + wav*8;
    float4 bL = *(const float4*)&b4[co0];
    float4 bH = *(const float4*)&b4[co0+4];
    float4 aL = *(const float4*)&a4[co0];
    float4 aH = *(const float4*)&a4[co0+4];
    float4 acc0 = bL, acc1 = bH;

    float4 wA[8], wB[8];
    K4_LOADW(wA, 0);
#pragma unroll 1
    for (int ci = 0; ci < 64; ci += 2) {
      K4_LOADW(wB, ci+1);
      K4_COMP(wA, ci);
      if (ci + 2 < 64) K4_LOADW(wA, ci+2);
      K4_COMP(wB, ci+1);
    }

    if (act) {
      float4 p0 = prelu4(acc0, aL);
      float4 p1 = prelu4(acc1, aH);
      float* d = c4o + (size_t)co0*9 + sp;
      d[0]  = p0.x; d[9]  = p0.y; d[18] = p0.z; d[27] = p0.w;
      d[36] = p1.x; d[45] = p1.y; d[54] = p1.z; d[63] = p1.w;
    }
  }
}

// ---------------- K5 v2 (R9-proven): coalesced-weight fc5, fc6, softmax, box reg --
__global__ __launch_bounds__(512) void k5_fc(
    const float* __restrict__ fc5w, const float* __restrict__ fc5b, const float* __restrict__ a5,
    const float* __restrict__ w6a, const float* __restrict__ b6a,
    const float* __restrict__ w6b, const float* __restrict__ b6b,
    const float* __restrict__ bboxes, const float* __restrict__ c4ws,
    float* __restrict__ ws_scores, float* __restrict__ ws_boxes, int box0)
{
  __shared__ float c4s[8*1152];            // 36.9 KB
  __shared__ float hs[8*256];
  __shared__ float l6[8][6];
  const int tid = threadIdx.x;
  const int lb0 = blockIdx.x * 8;          // chunk-local first box
  for (int idx4 = tid; idx4 < 2304; idx4 += 512)
    *(float4*)&c4s[idx4*4] = *(const float4*)&c4ws[(size_t)lb0*1152 + idx4*4];
  __syncthreads();

  const int wav = __builtin_amdgcn_readfirstlane(tid >> 6);  // 0..7
  const int lane = tid & 63;
  const int half = lane >> 5;
  const int l32  = lane & 31;
  const int b    = 2*(wav & 3) + half;     // box within block (0..7)
  const int ob   = (wav >> 2) * 128;       // o-range
  const float* cb = &c4s[b*1152 + l32*4];

#pragma unroll 1
  for (int oi = 0; oi < 128; oi++) {
    const int o = ob + oi;
    const float* wr = fc5w + (size_t)o*1152 + l32*4;
    float acc = 0.f;
#pragma unroll
    for (int j = 0; j < 9; j++) {
      float4 wv = *(const float4*)(wr + j*128);
      float4 cv = *(const float4*)(cb + j*128);
      acc = fmaf(cv.x, wv.x, acc);
      acc = fmaf(cv.y, wv.y, acc);
      acc = fmaf(cv.z, wv.z, acc);
      acc = fmaf(cv.w, wv.w, acc);
    }
    acc += __shfl_down(acc, 16, 32);
    acc += __shfl_down(acc,  8, 32);
    acc += __shfl_down(acc,  4, 32);
    acc += __shfl_down(acc,  2, 32);
    acc += __shfl_down(acc,  1, 32);
    if (l32 == 0) {
      float h = acc + fc5b[o];
      h = h >= 0.f ? h : a5[o]*h;
      hs[b*256 + o] = h;
    }
  }
  __syncthreads();

  if (tid < 48) {
    int bb = tid / 6, oi = tid % 6;
    const float* w = (oi < 2) ? &w6a[oi*256] : &w6b[(oi-2)*256];
    float d = (oi < 2) ? b6a[oi] : b6b[oi-2];
    const float* hh = &hs[bb*256];
    for (int k = 0; k < 256; k++) d += hh[k]*w[k];
    l6[bb][oi] = d;
  }
  __syncthreads();
  if (tid < 8) {
    int n = box0 + lb0 + tid;
    float l0 = l6[tid][0], l1 = l6[tid][1];
    float m = fmaxf(l0, l1);
    float e0 = expf(l0-m), e1 = expf(l1-m);
    float score = e1/(e0+e1);
    float r0 = l6[tid][2], r1 = l6[tid][3], r2 = l6[tid][4], r3 = l6[tid][5];
    float f0 = bboxes[n*4+0], f1 = bboxes[n*4+1], f2 = bboxes[n*4+2], f3 = bboxes[n*4+3];
    float bx1 = fmaxf(f0, 0.f), by1 = fmaxf(f1, 0.f);
    float bx2 = fminf(f2, 1024.f), by2 = fminf(f3, 1024.f);
    float w_ = bx2-bx1, h_ = by2-by1;
    ws_scores[n] = score;
    float4 ob2 = make_float4(bx1 + r0*w_, by1 + r1*h_, bx2 + r2*w_, by2 + r3*h_);
    *(float4*)&ws_boxes[n*4] = ob2;
  }
}

// ---------------- K6a: bitonic sort (score desc, idx asc), nv, sorted boxes -------
__global__ __launch_bounds__(1024) void k6a_sort(
    const float* __restrict__ ws_scores, const float* __restrict__ ws_boxes,
    int* __restrict__ sidx_ws, float* __restrict__ sbox_ws,
    float* __restrict__ area_ws, int* __restrict__ nv_ws)
{
  __shared__ float skey[2048];
  __shared__ int   sidx[2048];
  const int tid = threadIdx.x;
  for (int i = tid; i < 2048; i += 1024) {
    float s = ws_scores[i];
    skey[i] = (s >= 0.5f) ? s : -INFINITY;
    sidx[i] = i;
  }
  __syncthreads();
  for (int k = 2; k <= 2048; k <<= 1) {
    for (int j = k >> 1; j > 0; j >>= 1) {
      for (int i = tid; i < 2048; i += 1024) {
        int ixj = i ^ j;
        if (ixj > i) {
          float a = skey[i], b = skey[ixj];
          int ia = sidx[i], ib = sidx[ixj];
          bool up = ((i & k) == 0);
          bool aAfterB = (a < b) || (a == b && ia > ib);
          if (up ? aAfterB : !aAfterB) {
            skey[i] = b; skey[ixj] = a; sidx[i] = ib; sidx[ixj] = ia;
          }
        }
      }
      __syncthreads();
    }
  }
  if (tid == 0) nv_ws[0] = 2048;
  __syncthreads();
  for (int i = tid; i < 2048; i += 1024) {
    if (skey[i] == -INFINITY && (i == 0 || skey[i-1] != -INFINITY)) nv_ws[0] = i;
    int n = sidx[i];
    sidx_ws[i] = n;
    float4 b = *(const float4*)&ws_boxes[n*4];
    *(float4*)&sbox_ws[i*4] = b;
    area_ws[i] = (b.z-b.x)*(b.w-b.y);
  }
}

// ---------------- K6b: suppression bitmask matrix M[2048][32] ---------------------
__global__ __launch_bounds__(256) void k6b_iou(
    const int* __restrict__ nv_ws, const float* __restrict__ sbox_ws,
    const float* __restrict__ area_ws, unsigned long long* __restrict__ M)
{
  const int nv = nv_ws[0];
  int gt = blockIdx.x*256 + threadIdx.x;
  for (int w = gt; w < 2048*32; w += 128*256) {
    int i = w >> 5, wg = w & 31;
    if (i >= nv) continue;
    float4 bi = *(const float4*)&sbox_ws[i*4];
    float ai = area_ws[i];
    unsigned long long m = 0;
    int jbase = wg*64;
    if (jbase + 63 > i) {
      for (int jj = 0; jj < 64; jj++) {
        int j = jbase + jj;
        if (j <= i) continue;
        float4 bj = *(const float4*)&sbox_ws[j*4];
        float xx1 = fmaxf(bi.x, bj.x), yy1 = fmaxf(bi.y, bj.y);
        float xx2 = fminf(bi.z, bj.z), yy2 = fminf(bi.w, bj.w);
        float iw = fmaxf(xx2-xx1, 0.f), ih = fmaxf(yy2-yy1, 0.f);
        float inter = iw*ih;
        float iou = inter / (ai + area_ws[j] - inter + 1e-12f);
        if (iou > 0.5f) m |= (1ull << jj);
      }
    }
    M[w] = m;
  }
}

// ---------------- K6c: greedy scan (wave 0) + masked scatter to output ------------
__global__ __launch_bounds__(1024) void k6c_scan(
    const int* __restrict__ nv_ws, const int* __restrict__ sidx_ws,
    const float* __restrict__ sbox_ws, const unsigned long long* __restrict__ M,
    float* __restrict__ out)
{
  __shared__ unsigned long long Msh[128*32];
  __shared__ unsigned long long rem_sh[32];
  const int tid = threadIdx.x;
  const int nv = nv_ws[0];
  unsigned long long rem = 0;

  for (int c0 = 0; c0 < 2048; c0 += 128) {
    if (c0 >= nv) break;
    for (int w = tid; w < 128*32; w += 1024) {
      int i = c0 + (w >> 5);
      if (i < nv) Msh[w] = M[(size_t)i*32 + (w & 31)];
    }
    __syncthreads();
    if (tid < 64) {
      int iend = c0 + 128; if (iend > nv) iend = nv;
      for (int i = c0; i < iend; i += 4) {
        unsigned long long m0=0, m1=0, m2=0, m3=0;
        int base = (i - c0) << 5;
        if (tid < 32) {
          m0 = Msh[base + tid];
          if (i+1 < iend) m1 = Msh[base + 32 + tid];
          if (i+2 < iend) m2 = Msh[base + 64 + tid];
          if (i+3 < iend) m3 = Msh[base + 96 + tid];
        }
        unsigned long long rw = __shfl(rem, (i >> 6), 64);
        if (!((rw >> (i & 63)) & 1ull)) rem |= m0;
        if (i+1 < iend) {
          rw = __shfl(rem, ((i+1) >> 6), 64);
          if (!((rw >> ((i+1) & 63)) & 1ull)) rem |= m1;
        }
        if (i+2 < iend) {
          rw = __shfl(rem, ((i+2) >> 6), 64);
          if (!((rw >> ((i+2) & 63)) & 1ull)) rem |= m2;
        }
        if (i+3 < iend) {
          rw = __shfl(rem, ((i+3) >> 6), 64);
          if (!((rw >> ((i+3) & 63)) & 1ull)) rem |= m3;
        }
      }
    }
    __syncthreads();
  }
  if (tid < 32) rem_sh[tid] = rem;
  __syncthreads();
  for (int i = tid; i < 2048; i += 1024) {
    bool keep = (i < nv) && !((rem_sh[i >> 6] >> (i & 63)) & 1ull);
    int n = sidx_ws[i];
    float4 b = *(const float4*)&sbox_ws[i*4];
    float4 o = keep ? b : make_float4(0.f,0.f,0.f,0.f);
    *(float4*)&out[n*4] = o;
  }
}

// ---------------- host ------------------------------------------------------------
extern "C" void kernel_launch(void* const* d_in, const int* in_sizes, int n_in,
                              void* d_out, int out_size, void* d_ws, size_t ws_size,
                              hipStream_t stream)
{
  const float* bboxes = (const float*)d_in[0];
  const float* image  = (const float*)d_in[1];
  const float* w1 = (const float*)d_in[2];  const float* b1 = (const float*)d_in[3];  const float* a1 = (const float*)d_in[4];
  const float* w2 = (const float*)d_in[5];  const float* b2 = (const float*)d_in[6];  const float* a2 = (const float*)d_in[7];
  const float* w3 = (const float*)d_in[8];  const float* b3 = (const float*)d_in[9];  const float* a3 = (const float*)d_in[10];
  const float* w4 = (const float*)d_in[11]; const float* b4 = (const float*)d_in[12]; const float* a4 = (const float*)d_in[13];
  const float* fc5w = (const float*)d_in[14]; const float* fc5b = (const float*)d_in[15]; const float* a5 = (const float*)d_in[16];
  const float* w6a = (const float*)d_in[17]; const float* b6a = (const float*)d_in[18];
  const float* w6b = (const float*)d_in[19]; const float* b6b = (const float*)d_in[20];
  float* out = (float*)d_out;

  char* ws = (char*)d_ws;
  size_t off = 0;
  auto alloc = [&](size_t bytes) -> size_t {
    size_t p = off; off += (bytes + 255) & ~(size_t)255; return p;
  };
  size_t o_scores = alloc(NBOX*4);
  size_t o_boxes  = alloc(NBOX*16);
  size_t o_sidx   = alloc(NBOX*4);
  size_t o_sbox   = alloc(NBOX*16);
  size_t o_area   = alloc(NBOX*4);
  size_t o_nv     = alloc(256);
  size_t o_M      = alloc((size_t)NBOX*32*8);
  size_t fixed = off;
  const size_t perbox = (size_t)(P1_SZ + 7680 + 1024 + 1152) * 4;  // 113,152 B

  int B = NBOX;
  if (fixed + (size_t)B*perbox > ws_size) {
    size_t avail = ws_size > fixed ? ws_size - fixed : 0;
    B = (int)(avail / perbox);
    B &= ~7;                 // keep multiple of 8 for K5 grid / K3-K4 grouping
    if (B < 8) B = 8;
    if (B > NBOX) B = NBOX;
  }
  size_t o_p1 = alloc((size_t)B*P1_SZ*4);
  size_t o_p2 = alloc((size_t)B*7680*4);
  size_t o_p3 = alloc((size_t)B*1024*4);
  size_t o_c4 = alloc((size_t)B*1152*4);

  float* ws_scores = (float*)(ws + o_scores);
  float* ws_boxes  = (float*)(ws + o_boxes);
  int*   sidxp     = (int*)(ws + o_sidx);
  float* sboxp     = (float*)(ws + o_sbox);
  float* areap     = (float*)(ws + o_area);
  int*   nvp       = (int*)(ws + o_nv);
  unsigned long long* Mp = (unsigned long long*)(ws + o_M);
  float* p1p = (float*)(ws + o_p1);
  float* p2p = (float*)(ws + o_p2);
  float* p3p = (float*)(ws + o_p3);
  float* c4p = (float*)(ws + o_c4);

  for (int c0 = 0; c0 < NBOX; c0 += B) {
    int Bc = NBOX - c0; if (Bc > B) Bc = B;
    k1_crop_conv1<<<Bc, 256, 0, stream>>>(bboxes, image, w1, b1, a1, p1p, c0);
    k2_conv2<<<Bc, 512, 0, stream>>>(w2, b2, a2, p1p, p2p);
    k3_conv3<<<Bc/2, 512, 0, stream>>>(w3, b3, a3, p2p, p3p);
    k4_conv4<<<Bc/4, 512, 0, stream>>>(w4, b4, a4, p3p, c4p);
    k5_fc<<<Bc/8, 512, 0, stream>>>(fc5w, fc5b, a5, w6a, b6a, w6b, b6b,
                                    bboxes, c4p, ws_scores, ws_boxes, c0);
  }
  k6a_sort<<<1, 1024, 0, stream>>>(ws_scores, ws_boxes, sidxp, sboxp, areap, nvp);
  k6b_iou<<<128, 256, 0, stream>>>(nvp, sboxp, areap, Mp);
  k6c_scan<<<1, 1024, 0, stream>>>(nvp, sidxp, sboxp, Mp, out);
}